// Round 14
// baseline (179.171 us; speedup 1.0000x reference)
//
#include <hip/hip_runtime.h>

#define FEPS 1e-12f

typedef __attribute__((ext_vector_type(8))) short short8;   // 8 bf16 = 4 VGPR
typedef __attribute__((ext_vector_type(4))) short bf16x4;   // 4 bf16 = 2 VGPR
typedef __attribute__((ext_vector_type(4))) float floatx4;  // MFMA C/D

constexpr int NB = 64, D = 256, T = 4096, K = 64, S = 4;
constexpr int TC = 128;          // pixels per chunk (512B per d-row per load)
constexpr int TBLK = T / S;      // 1024 pixels per block
constexpr int NCH = TBLK / TC;   // 8 chunks

// f32 -> bf16 round-to-nearest-even
__device__ __forceinline__ unsigned short f2bf(float f) {
    unsigned u = __float_as_uint(f);
    return (unsigned short)((u + 0x7FFFu + ((u >> 16) & 1u)) >> 16);
}
__device__ __forceinline__ unsigned pk2(float a, float b) {
    return (unsigned)f2bf(a) | ((unsigned)f2bf(b) << 16);
}

// Workgroup barrier WITHOUT the implicit vmcnt(0) drain __syncthreads emits.
__device__ __forceinline__ void barrier_nd() {
    __builtin_amdgcn_sched_barrier(0);
    asm volatile("s_waitcnt lgkmcnt(0)" ::: "memory");
    __builtin_amdgcn_s_barrier();
    __builtin_amdgcn_sched_barrier(0);
}

// Fused: L2-norm factor + logits MFMA-GEMM + softmax + aggregation MFMA-GEMM.
// R14: attack the pattern-determined HBM ceiling (all TC=64 schedules cap at
// ~2.6 TB/s vs 6.9 sequential): TC=128 doubles the per-row DRAM run length
// (each load instr = 2 rows x 512B contiguous). One 1024-thread block/CU
// (grid 256 = S4 x NB), 16 waves, LDS 146.5KB:
//   0..131072   xt[2][64KB]  x tiles, tr-subtile layout, double-buffered
//               byte(d,t)=(d>>5)*8192+(t>>4)*1024+(d&31)*32+(t&15)*2
//   131072..147456  bm[k][128t ^ 8(k&7)] bf16
//   147456..147968  sqp[128] f32 (ds_add_f32 accumulated sumsq)
//   147968..150016  sps[128t][4] f32 softmax denom partials
// Same proven 3-barrier window, tr-read GEMM1 pipeline (stride 8192), JIT
// GEMM2. __launch_bounds__(1024,1) -> 4 waves/EU -> 128-VGPR cap.
__global__ __launch_bounds__(1024, 1)
void nv_main(const float* __restrict__ x, const float* __restrict__ w,
             float* __restrict__ vout, float* __restrict__ suma)
{
    __shared__ __align__(16) unsigned char smem[150016];
    unsigned short* bmm = (unsigned short*)(smem + 131072);
    float* sqp = (float*)(smem + 147456);
    float* sps = (float*)(smem + 147968);
    float* fb  = (float*)smem;

    const int tid = threadIdx.x;
    const int wv = tid >> 6, ln = tid & 63;
    const int m = ln & 15, g = ln >> 4;     // MFMA lane decomposition
    const int a = wv & 3, b = wv >> 2;      // GEMM1: k-band a, t-quarter b
    const int hi = ln >> 5, lo5 = ln & 31;  // staging decomposition
    const int bid = blockIdx.x;
    const int n = (bid & 7) * 8 + ((bid >> 3) & 7);   // XCD-confined n octet
    const int ts = bid >> 6;                           // t-split 0..3

    const float* xn = x + (size_t)n * D * T;

    // Resident W A-frags for k-band a = [16a, 16a+16)
    short8 wf[8];
    {
        const float* wp = w + (16 * a + m) * D + 8 * g;
        #pragma unroll
        for (int ks = 0; ks < 8; ++ks) {
            float4 q0 = *(const float4*)(wp + 32 * ks);
            float4 q1 = *(const float4*)(wp + 32 * ks + 4);
            union { short8 v; unsigned u[4]; } t_;
            t_.u[0] = pk2(q0.x, q0.y); t_.u[1] = pk2(q0.z, q0.w);
            t_.u[2] = pk2(q1.x, q1.y); t_.u[3] = pk2(q1.z, q1.w);
            wf[ks] = t_.v;
        }
    }

    floatx4 acc[4];                          // GEMM2 acc [mt(k)]; d = 16wv+m
    floatx4 fzero = {0.f, 0.f, 0.f, 0.f};
    #pragma unroll
    for (int p = 0; p < 4; ++p) acc[p] = fzero;
    float sa[4] = {0.f, 0.f, 0.f, 0.f};      // sum_t a for k = 16a+4g+reg

    float4 pvA[4], pvB[4];                   // split prefetch buffers
    float sqx, sqy, sqz, sqw;                // per-lane sumsq (4 t-columns)

    // issue half (rows 2*(s0..s0+3)+hi of this wave's 16-row band)
    auto issueH = [&](float4* pv, int cc, int s0) {
        const int tn = ts * TBLK + cc * TC + 4 * lo5;
        #pragma unroll
        for (int s = 0; s < 4; ++s)
            pv[s] = *(const float4*)(
                xn + (size_t)(16 * wv + 2 * (s0 + s) + hi) * T + tn);
    };
    // stage half into xt[buf] (subtiled bf16) + accumulate sumsq
    auto stageH = [&](const float4* pv, int buf, int s0) {
        #pragma unroll
        for (int s = 0; s < 4; ++s) {
            float4 v = pv[s];
            sqx = fmaf(v.x, v.x, sqx); sqy = fmaf(v.y, v.y, sqy);
            sqz = fmaf(v.z, v.z, sqz); sqw = fmaf(v.w, v.w, sqw);
            uint2 st2; st2.x = pk2(v.x, v.y); st2.y = pk2(v.z, v.w);
            const int dd = 16 * (wv & 1) + 2 * (s0 + s) + hi;   // d & 31
            *(uint2*)(smem + buf * 65536 + (wv >> 1) * 8192
                      + (lo5 >> 2) * 1024 + dd * 32 + (ln & 3) * 8) = st2;
        }
    };
    auto sqfin = [&]() {                     // fold rows hi=0/1, ds_add_f32
        sqx += __shfl_xor(sqx, 32); sqy += __shfl_xor(sqy, 32);
        sqz += __shfl_xor(sqz, 32); sqw += __shfl_xor(sqw, 32);
        if (hi == 0) {
            atomicAdd(&sqp[4 * lo5 + 0], sqx);
            atomicAdd(&sqp[4 * lo5 + 1], sqy);
            atomicAdd(&sqp[4 * lo5 + 2], sqz);
            atomicAdd(&sqp[4 * lo5 + 3], sqw);
        }
    };

    // ---- prologue: zero sqp; load + stage chunk 0 into xt[0]
    if (tid < 128) sqp[tid] = 0.f;
    issueH(pvA, 0, 0); issueH(pvB, 0, 4);
    barrier_nd();                            // zero visible before ds_adds
    sqx = 0.f; sqy = 0.f; sqz = 0.f; sqw = 0.f;
    stageH(pvA, 0, 0); stageH(pvB, 0, 4);
    sqfin();

    for (int c = 0; c < NCH; ++c) {
        const int cur = c & 1;
        barrier_nd();                        // B_A: publish xt[cur] + sqp

        // ---- issueA for chunk c+1 (in flight across whole window)
        if (c + 1 < NCH) issueH(pvA, c + 1, 0);

        // ---- r[t] = 1/max(||x[:,t]||,eps) (sqp holds the full sum)
        float r4[2];
        #pragma unroll
        for (int nt = 0; nt < 2; ++nt) {
            const int t = 32 * b + 16 * nt + m;
            r4[nt] = 1.f / fmaxf(sqrtf(sqp[t]), FEPS);
        }
        asm volatile("s_waitcnt lgkmcnt(0)" ::: "memory");
        __builtin_amdgcn_sched_barrier(0);

        // ---- GEMM1: z[16 k][32 t] = W * x, B-frags via HW transpose-read
        floatx4 z[2];
        z[0] = fzero; z[1] = fzero;
        const int trb = cur * 65536 + 2048 * b + 256 * g + 2 * m;
        bf16x4 hb[2][2][2];                  // [pipe][nt][half]
        {
            asm volatile("ds_read_b64_tr_b16 %0, %2 offset:0\n\t"
                         "ds_read_b64_tr_b16 %1, %2 offset:128"
                         : "=&v"(hb[0][0][0]), "=&v"(hb[0][0][1])
                         : "v"(trb));
            asm volatile("ds_read_b64_tr_b16 %0, %2 offset:0\n\t"
                         "ds_read_b64_tr_b16 %1, %2 offset:128"
                         : "=&v"(hb[0][1][0]), "=&v"(hb[0][1][1])
                         : "v"(trb + 1024));
        }
        #pragma unroll
        for (int ks = 0; ks < 8; ++ks) {
            const int pc = ks & 1;
            if (ks < 7) {
                const int an = trb + (ks + 1) * 8192;
                asm volatile("ds_read_b64_tr_b16 %0, %2 offset:0\n\t"
                             "ds_read_b64_tr_b16 %1, %2 offset:128"
                             : "=&v"(hb[pc ^ 1][0][0]), "=&v"(hb[pc ^ 1][0][1])
                             : "v"(an));
                asm volatile("ds_read_b64_tr_b16 %0, %2 offset:0\n\t"
                             "ds_read_b64_tr_b16 %1, %2 offset:128"
                             : "=&v"(hb[pc ^ 1][1][0]), "=&v"(hb[pc ^ 1][1][1])
                             : "v"(an + 1024));
                asm volatile("s_waitcnt lgkmcnt(4)" ::: "memory");
            } else {
                asm volatile("s_waitcnt lgkmcnt(0)" ::: "memory");
            }
            __builtin_amdgcn_sched_barrier(0);
            #pragma unroll
            for (int nt = 0; nt < 2; ++nt) {
                short8 bfr = __builtin_shufflevector(
                    hb[pc][nt][0], hb[pc][nt][1], 0, 1, 2, 3, 4, 5, 6, 7);
                z[nt] = __builtin_amdgcn_mfma_f32_16x16x32_bf16(
                    wf[ks], bfr, z[nt], 0, 0, 0);
            }
        }

        // ---- issueB for chunk c+1 (second burst)
        if (c + 1 < NCH) issueH(pvB, c + 1, 4);

        // ---- softmax over k (no max-sub: |logit| <= ||w_row|| ~ 1)
        float e[2][4], psum[2];
        #pragma unroll
        for (int nt = 0; nt < 2; ++nt) {
            const float r = r4[nt];
            float p = 0.f;
            #pragma unroll
            for (int reg = 0; reg < 4; ++reg) {
                float ex = __expf(z[nt][reg] * r);
                e[nt][reg] = ex; p += ex;
            }
            psum[nt] = p;
        }
        #pragma unroll
        for (int nt = 0; nt < 2; ++nt) {     // reduce over g: wave's 16 k's
            psum[nt] += __shfl_xor(psum[nt], 16);
            psum[nt] += __shfl_xor(psum[nt], 32);
        }
        if (g == 0) {
            #pragma unroll
            for (int nt = 0; nt < 2; ++nt)
                sps[(32 * b + 16 * nt + m) * 4 + a] = psum[nt];
        }
        barrier_nd();                        // B_B: publish sps
        #pragma unroll
        for (int nt = 0; nt < 2; ++nt) {
            const int t = 32 * b + 16 * nt + m;
            float4 sv = *(const float4*)(&sps[t * 4]);
            const float inv = 1.f / (sv.x + sv.y + sv.z + sv.w);
            const float br = inv * r4[nt];
            #pragma unroll
            for (int reg = 0; reg < 4; ++reg) {
                const int k = 16 * a + 4 * g + reg;
                bmm[k * 128 + (t ^ (8 * (k & 7)))] = f2bf(e[nt][reg] * br);
                sa[reg] += e[nt][reg] * inv;
            }
        }
        if (tid < 128) sqp[tid] = 0.f;       // reset for chunk c+1's adds
        barrier_nd();                        // B_C: publish bm + zeroed sqp

        // ---- GEMM2: acc[k][d=16wv+m] += b[k][t] * x[d][t]  (contract t=128)
        #pragma unroll
        for (int kt = 0; kt < 4; ++kt) {
            short8 bf = *(const short8*)(smem + cur * 65536 + (wv >> 1) * 8192
                        + (2 * kt + (g >> 1)) * 1024
                        + (16 * (wv & 1) + m) * 32 + (g & 1) * 16);
            #pragma unroll
            for (int mt = 0; mt < 4; ++mt) {
                const int k = 16 * mt + m;
                short8 af = *(const short8*)(
                    &bmm[k * 128 + ((32 * kt + 8 * g) ^ (8 * (k & 7)))]);
                acc[mt] = __builtin_amdgcn_mfma_f32_16x16x32_bf16(
                    af, bf, acc[mt], 0, 0, 0);
            }
        }

        // ---- stage chunk c+1 into other buffer + sumsq ds_adds
        if (c + 1 < NCH) {
            sqx = 0.f; sqy = 0.f; sqz = 0.f; sqw = 0.f;
            stageH(pvA, cur ^ 1, 0); stageH(pvB, cur ^ 1, 4);
            sqfin();
        }
    }

    // ---- epilogue: reassemble block partial in LDS, flush with 256B bursts
    barrier_nd();                            // xt[0] dead -> reuse as fb [k][d]
    #pragma unroll
    for (int mt = 0; mt < 4; ++mt)
        #pragma unroll
        for (int reg = 0; reg < 4; ++reg)
            fb[(16 * mt + 4 * g + reg) * D + 16 * wv + m] = acc[mt][reg];
    barrier_nd();
    {
        float* vs = vout + (size_t)n * K * D;
        #pragma unroll
        for (int j = 0; j < 16; ++j) {
            const int off = j * 1024 + tid;  // 64 lanes x 4B = 256B / wave
            atomicAdd(&vs[off], fb[off]);
        }
    }
    #pragma unroll
    for (int reg = 0; reg < 4; ++reg) {
        float v = sa[reg];
        v += __shfl_xor(v, 1); v += __shfl_xor(v, 2);
        v += __shfl_xor(v, 4); v += __shfl_xor(v, 8);
        if (m == 0) atomicAdd(&suma[n * K + 16 * a + 4 * g + reg], v);
    }
}

// per (n,k): subtract suma*centroid, intra-normalize over d, accum final sumsq
__global__ void nv_finish_row(const float* __restrict__ cent,
                              const float* __restrict__ suma,
                              float* __restrict__ out,
                              float* __restrict__ nsum)
{
    const int bid = blockIdx.x;          // n*64 + k
    const int nn = bid >> 6, k = bid & 63;
    const int d = threadIdx.x;
    float v = out[(size_t)bid * D + d] - suma[bid] * cent[k * D + d];
    float sv = v * v;
    #pragma unroll
    for (int msk = 1; msk < 64; msk <<= 1) sv += __shfl_xor(sv, msk);
    __shared__ float red[4];
    __shared__ float stot;
    if ((d & 63) == 0) red[d >> 6] = sv;
    __syncthreads();
    if (d == 0) stot = red[0] + red[1] + red[2] + red[3];
    __syncthreads();
    const float s = stot;
    const float inv = 1.f / fmaxf(sqrtf(s), FEPS);
    out[(size_t)bid * D + d] = v * inv;
    if (d == 0) atomicAdd(&nsum[nn], s * inv * inv);
}

// final L2 over the flattened (K*D) per n
__global__ void nv_final(float* __restrict__ out, const float* __restrict__ nsum) {
    const int idx = blockIdx.x * 256 + threadIdx.x;
    const int n = idx >> 14;             // /16384
    out[idx] *= 1.f / fmaxf(sqrtf(nsum[n]), FEPS);
}

extern "C" void kernel_launch(void* const* d_in, const int* in_sizes, int n_in,
                              void* d_out, int out_size, void* d_ws, size_t ws_size,
                              hipStream_t stream)
{
    const float* x    = (const float*)d_in[0];
    const float* w    = (const float*)d_in[1];
    const float* cent = (const float*)d_in[2];
    float* out = (float*)d_out;

    // ws layout: suma[NB*K] | nsum[NB]
    float* suma = (float*)d_ws;
    float* nsum = suma + NB * K;

    (void)hipMemsetAsync(d_ws, 0, (size_t)(NB * K + NB) * sizeof(float), stream);
    (void)hipMemsetAsync(d_out, 0, (size_t)NB * K * D * sizeof(float), stream);

    nv_main<<<S * NB, 1024, 0, stream>>>(x, w, out, suma);
    nv_finish_row<<<NB * K, 256, 0, stream>>>(cent, suma, out, nsum);
    nv_final<<<(NB * K * D) / 256, 256, 0, stream>>>(out, nsum);
}

// Round 15
// 97.192 us; speedup vs baseline: 1.8435x; 1.8435x over previous
//
#include <hip/hip_runtime.h>

#define FEPS 1e-12f

typedef __attribute__((ext_vector_type(8))) short short8;   // 8 bf16 = 4 VGPR
typedef __attribute__((ext_vector_type(4))) short bf16x4;   // 4 bf16 = 2 VGPR
typedef __attribute__((ext_vector_type(4))) float floatx4;  // MFMA C/D

constexpr int NB = 64, D = 256, T = 4096, K = 64, S = 8;
constexpr int TC = 64;           // pixels per chunk
constexpr int TBLK = T / S;      // 512 pixels per block
constexpr int NCH = TBLK / TC;   // 8 chunks

// f32 -> bf16 round-to-nearest-even
__device__ __forceinline__ unsigned short f2bf(float f) {
    unsigned u = __float_as_uint(f);
    return (unsigned short)((u + 0x7FFFu + ((u >> 16) & 1u)) >> 16);
}
__device__ __forceinline__ unsigned pk2(float a, float b) {
    return (unsigned)f2bf(a) | ((unsigned)f2bf(b) << 16);
}

// Workgroup barrier WITHOUT the implicit vmcnt(0) drain __syncthreads emits.
__device__ __forceinline__ void barrier_nd() {
    __builtin_amdgcn_sched_barrier(0);
    asm volatile("s_waitcnt lgkmcnt(0)" ::: "memory");
    __builtin_amdgcn_s_barrier();
    __builtin_amdgcn_sched_barrier(0);
}

// Fused: L2-norm factor + logits MFMA-GEMM + softmax + aggregation MFMA-GEMM.
// R13 structure (best stable): 3-barrier window, split pvA/pvB prefetch,
// tr-read GEMM1, JIT GEMM2 A-frags, t-major sqp.
// x tile in LDS in tr-read subtile layout:
//   byte(d,t) = (d>>5)*4096 + (t>>4)*1024 + (d&31)*32 + (t&15)*2  [32x16 bf16]
// TC=64: every global load = 4 rows x 256B contiguous. LDS 75KB -> 2
// blocks/CU; __launch_bounds__(512,2) -> 128-VGPR cap (measured, no spill).
__global__ __launch_bounds__(512, 2)
void nv_main(const float* __restrict__ x, const float* __restrict__ w,
             float* __restrict__ vout, float* __restrict__ suma)
{
    __shared__ __align__(16) unsigned char smem[76800];
    // 0      .. 65536 : xt[2][32768]  x tiles (subtiled bf16, double-buffered)
    // 65536  .. 73728 : bm [k][64 t ^ 8(k&7)] bf16 (8 KB)
    // 73728  .. 74752 : sps[64 t][4] f32 softmax denom partials
    // 74752  .. 76800 : sqp[64 t][8 wv] f32 sumsq partials (t-major)
    unsigned short* bmm = (unsigned short*)(smem + 65536);
    float* sps = (float*)(smem + 73728);
    float* sqp = (float*)(smem + 74752);
    float* fb  = (float*)smem;

    const int tid = threadIdx.x;
    const int wv = tid >> 6, ln = tid & 63;
    const int m = ln & 15, g = ln >> 4;     // MFMA/staging lane decomposition
    const int a = wv & 3, b = wv >> 2;      // GEMM1: k-band a, t-half b
    const int bid = blockIdx.x;
    const int n = (bid & 7) * 8 + ((bid >> 3) & 7);   // XCD-confined n octet
    const int ts = bid >> 6;                           // t-split 0..7

    const float* xn = x + (size_t)n * D * T;

    // Resident W A-frags for k-band a = [16a, 16a+16)
    short8 wf[8];
    {
        const float* wp = w + (16 * a + m) * D + 8 * g;
        #pragma unroll
        for (int ks = 0; ks < 8; ++ks) {
            float4 q0 = *(const float4*)(wp + 32 * ks);
            float4 q1 = *(const float4*)(wp + 32 * ks + 4);
            union { short8 v; unsigned u[4]; } t_;
            t_.u[0] = pk2(q0.x, q0.y); t_.u[1] = pk2(q0.z, q0.w);
            t_.u[2] = pk2(q1.x, q1.y); t_.u[3] = pk2(q1.z, q1.w);
            wf[ks] = t_.v;
        }
    }

    floatx4 acc[4][2];                       // GEMM2 acc [mt(k)][nt2(d)]
    floatx4 fzero = {0.f, 0.f, 0.f, 0.f};
    #pragma unroll
    for (int p = 0; p < 4; ++p) { acc[p][0] = fzero; acc[p][1] = fzero; }
    float sa[4] = {0.f, 0.f, 0.f, 0.f};      // sum_t a for k = 16a+4g+reg

    float4 pvA[4], pvB[4];                   // split prefetch buffers
    float4 sq4;                              // sumsq carry stageA->stageB

    // issue half H (rows s0..s0+3) of chunk cc
    auto issueH = [&](float4* pv, int cc, int s0) {
        const int tn = ts * TBLK + cc * TC;
        #pragma unroll
        for (int s = 0; s < 4; ++s)
            pv[s] = *(const float4*)(
                xn + (size_t)(32 * wv + 4 * (s0 + s) + g) * T + tn + 4 * m);
    };
    // stage half H into xt[bufsel] (subtiled bf16), accumulate sq4
    auto stageH = [&](const float4* pv, int bufsel, int s0) {
        #pragma unroll
        for (int s = 0; s < 4; ++s) {
            float4 v = pv[s];
            sq4.x = fmaf(v.x, v.x, sq4.x); sq4.y = fmaf(v.y, v.y, sq4.y);
            sq4.z = fmaf(v.z, v.z, sq4.z); sq4.w = fmaf(v.w, v.w, sq4.w);
            uint2 st2; st2.x = pk2(v.x, v.y); st2.y = pk2(v.z, v.w);
            const int dd = 4 * (s0 + s) + g;     // d & 31 (d = 32wv + dd)
            *(uint2*)(smem + bufsel * 32768 + wv * 4096 + (m >> 2) * 1024
                      + dd * 32 + (m & 3) * 8) = st2;
        }
    };
    auto sqzero = [&]() {
        sq4.x = 0.f; sq4.y = 0.f; sq4.z = 0.f; sq4.w = 0.f;
    };
    auto sqreduce = [&]() {                  // reduce over g, publish t-major
        #pragma unroll
        for (int msk = 16; msk <= 32; msk <<= 1) {
            sq4.x += __shfl_xor(sq4.x, msk); sq4.y += __shfl_xor(sq4.y, msk);
            sq4.z += __shfl_xor(sq4.z, msk); sq4.w += __shfl_xor(sq4.w, msk);
        }
        if (g == 0) {
            sqp[(4 * m + 0) * 8 + wv] = sq4.x;
            sqp[(4 * m + 1) * 8 + wv] = sq4.y;
            sqp[(4 * m + 2) * 8 + wv] = sq4.z;
            sqp[(4 * m + 3) * 8 + wv] = sq4.w;
        }
    };

    // ---- prologue: load + stage chunk 0 into xt[0]
    issueH(pvA, 0, 0); issueH(pvB, 0, 4);
    sqzero();
    stageH(pvA, 0, 0); stageH(pvB, 0, 4);
    sqreduce();

    for (int c = 0; c < NCH; ++c) {
        const int cur = c & 1;
        barrier_nd();                        // B_A: publish xt[cur] + sqp

        // ---- issueA for chunk c+1 (in flight across whole window)
        if (c + 1 < NCH) issueH(pvA, c + 1, 0);

        // ---- r[t] = 1/max(||x[:,t]||,eps): 2 x b128 per t (t-major sqp)
        float r4[2];
        #pragma unroll
        for (int nt = 0; nt < 2; ++nt) {
            const int t = 32 * b + 16 * nt + m;
            float4 p0 = *(const float4*)(&sqp[t * 8]);
            float4 p1 = *(const float4*)(&sqp[t * 8 + 4]);
            float ss = ((p0.x + p0.y) + (p0.z + p0.w))
                     + ((p1.x + p1.y) + (p1.z + p1.w));
            r4[nt] = 1.f / fmaxf(sqrtf(ss), FEPS);
        }
        asm volatile("s_waitcnt lgkmcnt(0)" ::: "memory");
        __builtin_amdgcn_sched_barrier(0);

        // ---- GEMM1: z[16 k][32 t] = W * x, B-frags via HW transpose-read.
        floatx4 z[2];
        z[0] = fzero; z[1] = fzero;
        const int trb = cur * 32768 + 2048 * b + 256 * g + 2 * m;
        bf16x4 hb[2][2][2];                  // [pipe][nt][half]
        {
            asm volatile("ds_read_b64_tr_b16 %0, %2 offset:0\n\t"
                         "ds_read_b64_tr_b16 %1, %2 offset:128"
                         : "=&v"(hb[0][0][0]), "=&v"(hb[0][0][1])
                         : "v"(trb));
            asm volatile("ds_read_b64_tr_b16 %0, %2 offset:0\n\t"
                         "ds_read_b64_tr_b16 %1, %2 offset:128"
                         : "=&v"(hb[0][1][0]), "=&v"(hb[0][1][1])
                         : "v"(trb + 1024));
        }
        #pragma unroll
        for (int ks = 0; ks < 8; ++ks) {
            const int pc = ks & 1;
            if (ks < 7) {
                const int an = trb + (ks + 1) * 4096;
                asm volatile("ds_read_b64_tr_b16 %0, %2 offset:0\n\t"
                             "ds_read_b64_tr_b16 %1, %2 offset:128"
                             : "=&v"(hb[pc ^ 1][0][0]), "=&v"(hb[pc ^ 1][0][1])
                             : "v"(an));
                asm volatile("ds_read_b64_tr_b16 %0, %2 offset:0\n\t"
                             "ds_read_b64_tr_b16 %1, %2 offset:128"
                             : "=&v"(hb[pc ^ 1][1][0]), "=&v"(hb[pc ^ 1][1][1])
                             : "v"(an + 1024));
                asm volatile("s_waitcnt lgkmcnt(4)" ::: "memory");
            } else {
                asm volatile("s_waitcnt lgkmcnt(0)" ::: "memory");
            }
            __builtin_amdgcn_sched_barrier(0);
            #pragma unroll
            for (int nt = 0; nt < 2; ++nt) {
                short8 bfr = __builtin_shufflevector(
                    hb[pc][nt][0], hb[pc][nt][1], 0, 1, 2, 3, 4, 5, 6, 7);
                z[nt] = __builtin_amdgcn_mfma_f32_16x16x32_bf16(
                    wf[ks], bfr, z[nt], 0, 0, 0);
            }
        }

        // ---- issueB for chunk c+1 (second burst; flight ~half window)
        if (c + 1 < NCH) issueH(pvB, c + 1, 4);

        // ---- softmax over k (no max-sub: |logit| <= ||w_row|| ~ 1)
        float e[2][4], psum[2];
        #pragma unroll
        for (int nt = 0; nt < 2; ++nt) {
            const float r = r4[nt];
            float p = 0.f;
            #pragma unroll
            for (int reg = 0; reg < 4; ++reg) {
                float ex = __expf(z[nt][reg] * r);
                e[nt][reg] = ex; p += ex;
            }
            psum[nt] = p;
        }
        #pragma unroll
        for (int nt = 0; nt < 2; ++nt) {     // reduce over g: wave's 16 k's
            psum[nt] += __shfl_xor(psum[nt], 16);
            psum[nt] += __shfl_xor(psum[nt], 32);
        }
        if (g == 0) {
            #pragma unroll
            for (int nt = 0; nt < 2; ++nt)
                sps[(32 * b + 16 * nt + m) * 4 + a] = psum[nt];
        }
        barrier_nd();                        // B_B: publish sps
        #pragma unroll
        for (int nt = 0; nt < 2; ++nt) {
            const int t = 32 * b + 16 * nt + m;
            float4 sv = *(const float4*)(&sps[t * 4]);
            const float inv = 1.f / (sv.x + sv.y + sv.z + sv.w);
            const float br = inv * r4[nt];
            #pragma unroll
            for (int reg = 0; reg < 4; ++reg) {
                const int k = 16 * a + 4 * g + reg;
                bmm[k * TC + (t ^ (8 * (k & 7)))] = f2bf(e[nt][reg] * br);
                sa[reg] += e[nt][reg] * inv;
            }
        }

        // ---- stageA chunk c+1 -> xt[cur^1] (free since B_A)
        sqzero();
        if (c + 1 < NCH) stageH(pvA, cur ^ 1, 0);
        barrier_nd();                        // B_C: publish bm

        // ---- GEMM2: acc[k][d] += b[k][t] * x[d][t]  (contract t=64)
        #pragma unroll
        for (int kt = 0; kt < 2; ++kt) {
            short8 bf[2];
            #pragma unroll
            for (int nt2 = 0; nt2 < 2; ++nt2)
                bf[nt2] = *(const short8*)(smem + cur * 32768 + wv * 4096
                           + (2 * kt + (g >> 1)) * 1024
                           + (16 * nt2 + m) * 32 + (g & 1) * 16);
            #pragma unroll
            for (int mt = 0; mt < 4; ++mt) {
                const int k = 16 * mt + m;
                short8 af = *(const short8*)(
                    &bmm[k * TC + ((32 * kt + 8 * g) ^ (8 * (k & 7)))]);
                #pragma unroll
                for (int nt2 = 0; nt2 < 2; ++nt2)
                    acc[mt][nt2] = __builtin_amdgcn_mfma_f32_16x16x32_bf16(
                        af, bf[nt2], acc[mt][nt2], 0, 0, 0);
            }
        }

        // ---- stageB chunk c+1; publish sqp for next window
        if (c + 1 < NCH) { stageH(pvB, cur ^ 1, 4); sqreduce(); }
    }

    // ---- epilogue: reassemble block partial in LDS, flush with 256B bursts
    barrier_nd();                            // xt dead -> reuse as fb [k][d]
    #pragma unroll
    for (int mt = 0; mt < 4; ++mt)
        #pragma unroll
        for (int nt2 = 0; nt2 < 2; ++nt2)
            #pragma unroll
            for (int reg = 0; reg < 4; ++reg)
                fb[(16 * mt + 4 * g + reg) * D + 32 * wv + 16 * nt2 + m] =
                    acc[mt][nt2][reg];
    barrier_nd();
    {
        float* vs = vout + (size_t)n * K * D;
        #pragma unroll
        for (int j = 0; j < 32; ++j) {
            const int off = wv * 2048 + j * 64 + ln;  // 64 lanes x 4B = 256B
            atomicAdd(&vs[off], fb[off]);
        }
    }
    #pragma unroll
    for (int reg = 0; reg < 4; ++reg) {
        float v = sa[reg];
        v += __shfl_xor(v, 1); v += __shfl_xor(v, 2);
        v += __shfl_xor(v, 4); v += __shfl_xor(v, 8);
        if (m == 0) atomicAdd(&suma[n * K + 16 * a + 4 * g + reg], v);
    }
}

// per (n,k): subtract suma*centroid, intra-normalize over d, and apply the
// final flat L2 in closed form: after intra-norm every row has unit norm, so
// ||flat|| = sqrt(K) = 8 exactly -> fold 1/8 here and skip the extra pass.
__global__ void nv_finish_row(const float* __restrict__ cent,
                              const float* __restrict__ suma,
                              float* __restrict__ out)
{
    const int bid = blockIdx.x;          // n*64 + k
    const int k = bid & 63;
    const int d = threadIdx.x;
    float v = out[(size_t)bid * D + d] - suma[bid] * cent[k * D + d];
    float sv = v * v;
    #pragma unroll
    for (int msk = 1; msk < 64; msk <<= 1) sv += __shfl_xor(sv, msk);
    __shared__ float red[4];
    __shared__ float stot;
    if ((d & 63) == 0) red[d >> 6] = sv;
    __syncthreads();
    if (d == 0) stot = red[0] + red[1] + red[2] + red[3];
    __syncthreads();
    const float inv = 0.125f / fmaxf(sqrtf(stot), FEPS);   // intra-norm * 1/sqrt(K)
    out[(size_t)bid * D + d] = v * inv;
}

extern "C" void kernel_launch(void* const* d_in, const int* in_sizes, int n_in,
                              void* d_out, int out_size, void* d_ws, size_t ws_size,
                              hipStream_t stream)
{
    const float* x    = (const float*)d_in[0];
    const float* w    = (const float*)d_in[1];
    const float* cent = (const float*)d_in[2];
    float* out = (float*)d_out;

    float* suma = (float*)d_ws;          // NB*K floats

    (void)hipMemsetAsync(d_ws, 0, (size_t)NB * K * sizeof(float), stream);
    (void)hipMemsetAsync(d_out, 0, (size_t)NB * K * D * sizeof(float), stream);

    nv_main<<<S * NB, 512, 0, stream>>>(x, w, out, suma);
    nv_finish_row<<<NB * K, 256, 0, stream>>>(cent, suma, out);
}